// Round 6
// baseline (128.204 us; speedup 1.0000x reference)
//
#include <hip/hip_runtime.h>
#include <hip/hip_bf16.h>

#define BB 16
#define LL 2048
#define DD 256
#define NN 16
#define RR 16
#define CH 64
#define LC (LL/CH)   /* 32 */

static __device__ __forceinline__ float bf2f(unsigned short u) {
    return __uint_as_float(((unsigned)u) << 16);
}
static __device__ __forceinline__ unsigned short f2bf(float f) {
    unsigned u = __float_as_uint(f);
    u += 0x7FFFu + ((u >> 16) & 1u);
    return (unsigned short)(u >> 16);
}

typedef __attribute__((ext_vector_type(8))) short bf16x8;
typedef __attribute__((ext_vector_type(4))) short bf16x4;
typedef __attribute__((ext_vector_type(4))) float f32x4;

// e[n] = E^(n+1), depth-4 product tree (full-rate VALU instead of trans pipe)
static __device__ __forceinline__ void pow_tree(float E, float* e) {
    e[0] = E;
    e[1] = E * E;
    e[2] = e[1] * E;
    e[3] = e[1] * e[1];
    e[4] = e[3] * e[0];  e[5] = e[3] * e[1];  e[6] = e[3] * e[2];  e[7] = e[3] * e[3];
    e[8] = e[7] * e[0];  e[9] = e[7] * e[1];  e[10] = e[7] * e[2]; e[11] = e[7] * e[3];
    e[12] = e[7] * e[4]; e[13] = e[7] * e[5]; e[14] = e[7] * e[6]; e[15] = e[7] * e[7];
}

// ---------------------------------------------------------------------------
// prep: Wxt[n][k] = xw[k][n] (bf16, n padded 48->64 with zeros). grid 16x256
// ---------------------------------------------------------------------------
__global__ __launch_bounds__(256) void k_prep_wx(
    const float* __restrict__ xw, unsigned short* __restrict__ Wxt)
{
    const int idx = blockIdx.x * 256 + threadIdx.x;   // 0..4095
    const int n  = idx >> 6;
    const int k0 = (idx & 63) * 4;
    #pragma unroll
    for (int i = 0; i < 4; ++i) {
        float v = (n < 48) ? xw[(size_t)(k0 + i) * 48 + n] : 0.f;
        Wxt[(size_t)n * DD + k0 + i] = f2bf(v);
    }
}

// ---------------------------------------------------------------------------
// Transpose glu_w (256x512 fp32) -> Wt (512x256 bf16)
// ---------------------------------------------------------------------------
__global__ __launch_bounds__(256) void k_transpose(
    const float* __restrict__ W, unsigned short* __restrict__ Wt)
{
    __shared__ unsigned short s[32][33];
    const int bx = blockIdx.x; // n tile (16)
    const int by = blockIdx.y; // k tile (8)
    const int t = threadIdx.x;
    const int r = t >> 5, cc = t & 31;
    #pragma unroll
    for (int i = 0; i < 4; ++i)
        s[r + 8*i][cc] = f2bf(W[(size_t)(by*32 + r + 8*i)*512 + bx*32 + cc]);
    __syncthreads();
    #pragma unroll
    for (int i = 0; i < 4; ++i)
        Wt[(size_t)(bx*32 + r + 8*i)*256 + by*32 + cc] = s[cc][r + 8*i];
}

// ---------------------------------------------------------------------------
// Kernel A (fused): LN + x_proj MFMA + dt_proj + softplus.
// 32 rows/block, 1024 blocks, 256 threads. Small operands in LDS.
// ---------------------------------------------------------------------------
__global__ __launch_bounds__(256) void k_ln_fused(
    const float* __restrict__ x,
    const float* __restrict__ ln_w,
    const float* __restrict__ ln_b,
    const unsigned short* __restrict__ Wxt,  // 64x256 bf16
    const float* __restrict__ dtw,           // 16x256
    const float* __restrict__ dtb,           // 256
    unsigned short* __restrict__ xln,
    unsigned short* __restrict__ delta,
    float* __restrict__ Bv,
    float* __restrict__ Cv)
{
    const int t = threadIdx.x;
    const int m0 = blockIdx.x * 32;
    const int row = t >> 3, seg = t & 7;
    const int grow = m0 + row;

    __shared__ unsigned short As[32][264];
    __shared__ float sdt[32][20];
    __shared__ float sdtw[16*256];
    __shared__ float slnw[256], slnb[256], sdtb[256];

    // ---- stage small operands into LDS
    {
        const int tt = t & 63;
        if (t < 64)       *(float4*)&slnw[tt*4] = *(const float4*)&ln_w[tt*4];
        else if (t < 128) *(float4*)&slnb[tt*4] = *(const float4*)&ln_b[tt*4];
        else if (t < 192) *(float4*)&sdtb[tt*4] = *(const float4*)&dtb[tt*4];
        #pragma unroll
        for (int k = 0; k < 4; ++k)
            *(float4*)&sdtw[(k*256 + t)*4] = *(const float4*)&dtw[(k*256 + t)*4];
    }

    // ---- load x (strided map) into registers
    float v[32];
    #pragma unroll
    for (int i = 0; i < 8; ++i)
        *(float4*)&v[i*4] = *(const float4*)(x + (size_t)grow*DD + i*32 + seg*4);

    // ---- LN stats: intra-thread + 8-lane shuffle reduce
    float s = 0.f, q = 0.f;
    #pragma unroll
    for (int i = 0; i < 32; ++i) { s += v[i]; q = fmaf(v[i], v[i], q); }
    #pragma unroll
    for (int o = 1; o < 8; o <<= 1) {
        s += __shfl_xor(s, o);
        q += __shfl_xor(q, o);
    }
    const float mu = s * (1.f/DD);
    const float rs = rsqrtf(q * (1.f/DD) - mu*mu + 1e-5f);
    __syncthreads();   // staging complete

    // ---- normalize, cast, write global + LDS A-tile
    unsigned short o16[32];
    #pragma unroll
    for (int i = 0; i < 8; ++i) {
        const int c = i*32 + seg*4;
        const float4 wv = *(const float4*)&slnw[c];
        const float4 bv = *(const float4*)&slnb[c];
        o16[i*4+0] = f2bf((v[i*4+0]-mu)*rs*wv.x + bv.x);
        o16[i*4+1] = f2bf((v[i*4+1]-mu)*rs*wv.y + bv.y);
        o16[i*4+2] = f2bf((v[i*4+2]-mu)*rs*wv.z + bv.z);
        o16[i*4+3] = f2bf((v[i*4+3]-mu)*rs*wv.w + bv.w);
    }
    #pragma unroll
    for (int i = 0; i < 8; ++i) {
        const int c = i*32 + seg*4;
        *(bf16x4*)&xln[(size_t)grow*DD + c] = *(bf16x4*)&o16[i*4];
        *(bf16x4*)&As[row][c]               = *(bf16x4*)&o16[i*4];
    }
    __syncthreads();

    // ---- x_proj MFMA: (32x256)@(256x48), B-fragments direct from global Wxt
    const int w = t >> 6, lane = t & 63;
    const int cl = lane & 15, rq = lane >> 4;
    const int mh = (w & 1) * 16;
    const int nh = (w >> 1) * 32;
    f32x4 acc0 = {0.f,0.f,0.f,0.f}, acc1 = {0.f,0.f,0.f,0.f};
    #pragma unroll
    for (int k0 = 0; k0 < 256; k0 += 32) {
        const bf16x8 a  = *(const bf16x8*)&As[mh + cl][k0 + rq*8];
        const bf16x8 b0 = *(const bf16x8*)&Wxt[(size_t)(nh + cl)*DD + k0 + rq*8];
        acc0 = __builtin_amdgcn_mfma_f32_16x16x32_bf16(a, b0, acc0, 0, 0, 0);
        if (w < 2) {
            const bf16x8 b1 = *(const bf16x8*)&Wxt[(size_t)(nh + 16 + cl)*DD + k0 + rq*8];
            acc1 = __builtin_amdgcn_mfma_f32_16x16x32_bf16(a, b1, acc1, 0, 0, 0);
        }
    }
    if (w < 2) {   // cols 0..15 -> dt (LDS), cols 16..31 -> Bv
        #pragma unroll
        for (int r = 0; r < 4; ++r) {
            sdt[mh + rq*4 + r][cl] = acc0[r];
            Bv[(size_t)(m0 + mh + rq*4 + r)*NN + cl] = acc1[r];
        }
    } else {       // cols 32..47 -> Cv
        #pragma unroll
        for (int r = 0; r < 4; ++r)
            Cv[(size_t)(m0 + mh + rq*4 + r)*NN + cl] = acc0[r];
    }
    __syncthreads();

    // ---- dt_proj (K=16) + softplus, all operands from LDS
    float dt[16];
    #pragma unroll
    for (int j = 0; j < 16; ++j) dt[j] = sdt[row][j];
    #pragma unroll
    for (int i = 0; i < 8; ++i) {
        const int c = i*32 + seg*4;
        float4 a4 = *(const float4*)&sdtb[c];
        #pragma unroll
        for (int j = 0; j < 16; ++j) {
            const float4 w4 = *(const float4*)&sdtw[j*256 + c];
            a4.x = fmaf(dt[j], w4.x, a4.x);
            a4.y = fmaf(dt[j], w4.y, a4.y);
            a4.z = fmaf(dt[j], w4.z, a4.z);
            a4.w = fmaf(dt[j], w4.w, a4.w);
        }
        unsigned short d16[4];
        #pragma unroll
        for (int jj = 0; jj < 4; ++jj) {
            const float ac = (&a4.x)[jj];
            const float sp = (ac > 15.f) ? ac
                : 0.69314718f * log2f(1.f + exp2f(ac * 1.44269504f));
            d16[jj] = f2bf(sp);
        }
        *(bf16x4*)&delta[(size_t)grow*DD + c] = *(bf16x4*)&d16[0];
    }
}

// ---------------------------------------------------------------------------
// scan pass 1 — per-chunk local state S and delta-sum. grid B*CH, 256 thr
// ---------------------------------------------------------------------------
template<bool FAST>
__device__ __forceinline__ void scan1_impl(
    const unsigned short* __restrict__ delta,
    const unsigned short* __restrict__ xln,
    const float (*sB)[16],
    const float* al, int b, int c, int d,
    float* h, float* dsum)
{
    const int l0 = c * LC;
    for (int l = 0; l < LC; ++l) {
        const size_t base = (size_t)b*LL + l0 + l;
        const float dl = bf2f(delta[base*DD + d]);
        const float xl = bf2f(xln[base*DD + d]);
        const float dx = dl * xl;
        *dsum += dl;
        float e[NN];
        if (FAST) pow_tree(exp2f(al[0]*dl), e);
        else {
            #pragma unroll
            for (int n = 0; n < NN; ++n) e[n] = exp2f(al[n]*dl);
        }
        #pragma unroll
        for (int n = 0; n < NN; ++n)
            h[n] = fmaf(e[n], h[n], dx * sB[l][n]);
    }
}

__global__ __launch_bounds__(256) void k_scan1(
    const unsigned short* __restrict__ delta,
    const unsigned short* __restrict__ xln,
    const float* __restrict__ Bv,
    const float* __restrict__ A_log,
    float* __restrict__ S, float* __restrict__ Dsum)
{
    const int blk = blockIdx.x;
    const int c = blk & (CH-1);
    const int b = blk >> 6;
    const int d = threadIdx.x;
    __shared__ float sB[LC][16];
    if (d < 128) {
        const int l = d >> 2, q = (d & 3) * 4;
        *(float4*)&sB[l][q] = *(const float4*)&Bv[((size_t)b*LL + c*LC + l)*NN + q];
    }
    float al[NN];
    bool fast = true;
    #pragma unroll
    for (int n = 0; n < NN; ++n) {
        al[n] = -expf(A_log[d*NN + n]) * 1.44269504f;
        fast = fast && (fabsf(al[n] - (n+1)*al[0]) <= 1e-3f*fabsf(al[n]) + 1e-6f);
    }
    float h[NN];
    #pragma unroll
    for (int n = 0; n < NN; ++n) h[n] = 0.f;
    float dsum = 0.f;
    __syncthreads();
    if (fast) scan1_impl<true >(delta, xln, sB, al, b, c, d, h, &dsum);
    else      scan1_impl<false>(delta, xln, sB, al, b, c, d, h, &dsum);
    const size_t o = (size_t)blk * NN * DD + d;
    #pragma unroll
    for (int n = 0; n < NN; ++n) S[o + n*DD] = h[n];
    Dsum[(size_t)blk*DD + d] = dsum;
}

// ---------------------------------------------------------------------------
// combine: sequential fold over chunks -> per-chunk incoming state Hin.
// block = (b,n), threads = d. 8-deep load batching to hide HBM/L2 latency
// (the fold itself is a 64-long dependent chain; loads are not).
// ---------------------------------------------------------------------------
__global__ __launch_bounds__(256) void k_combine(
    const float* __restrict__ S, const float* __restrict__ Dsum,
    const float* __restrict__ A_log, float* __restrict__ Hin)
{
    const int bi = blockIdx.x;
    const int d = threadIdx.x;
    const int n = bi & 15;
    const int b = bi >> 4;
    const float al = -expf(A_log[d*NN + n]) * 1.44269504f;
    float h = 0.f;
    for (int c0 = 0; c0 < CH; c0 += 8) {
        float ds8[8], s8[8];
        #pragma unroll
        for (int i = 0; i < 8; ++i) {
            const size_t blk = (size_t)b*CH + c0 + i;
            ds8[i] = Dsum[blk*DD + d];
            s8[i]  = S[(blk*NN + n)*DD + d];
        }
        #pragma unroll
        for (int i = 0; i < 8; ++i) {
            const size_t blk = (size_t)b*CH + c0 + i;
            Hin[(blk*NN + n)*DD + d] = h;
            h = fmaf(exp2f(al * ds8[i]), h, s8[i]);
        }
    }
}

// ---------------------------------------------------------------------------
// scan pass 2 + GLU fused: scan -> gelu -> g tile in LDS -> MFMA GEMM vs Wt
// -> bias + sigmoid gate + skip -> out.  One block per (b, chunk): M-tile=32.
// Wave w owns output cols [w*64, w*64+64) of BOTH halves (lo & hi) so the
// gate pairs within-thread. 128 MFMA/wave; Wt streamed from L2.
// ---------------------------------------------------------------------------
template<bool FAST>
__device__ __forceinline__ void scan2_impl(
    const unsigned short* __restrict__ delta,
    const unsigned short* __restrict__ xln,
    const float (*sB)[16], const float (*sC)[16],
    unsigned short (*gs)[264],
    const float* al, int b, int c, int d,
    float* h, float dsk)
{
    const int l0 = c * LC;
    for (int l = 0; l < LC; ++l) {
        const size_t base = (size_t)b*LL + l0 + l;
        const float dl = bf2f(delta[base*DD + d]);
        const float xl = bf2f(xln[base*DD + d]);
        const float dx = dl * xl;
        float e[NN];
        if (FAST) pow_tree(exp2f(al[0]*dl), e);
        else {
            #pragma unroll
            for (int n = 0; n < NN; ++n) e[n] = exp2f(al[n]*dl);
        }
        float y = 0.f;
        #pragma unroll
        for (int n = 0; n < NN; ++n) {
            h[n] = fmaf(e[n], h[n], dx * sB[l][n]);
            y = fmaf(h[n], sC[l][n], y);
        }
        const float vv = y + xl * dsk;
        // gelu (tanh form)
        const float u  = 0.7978845608f * (vv + 0.044715f*vv*vv*vv);
        const float t2 = exp2f(2.8853900818f * u);
        const float th = 1.f - 2.f/(t2 + 1.f);
        gs[l][d] = f2bf(0.5f * vv * (1.f + th));
    }
}

__global__ __launch_bounds__(256) void k_scan2glu(
    const unsigned short* __restrict__ delta,
    const unsigned short* __restrict__ xln,
    const float* __restrict__ Bv,
    const float* __restrict__ Cv,
    const float* __restrict__ A_log,
    const float* __restrict__ Hin,
    const float* __restrict__ Dskip,
    const unsigned short* __restrict__ Wt,   // 512x256 bf16
    const float* __restrict__ gb,            // 512
    const float* __restrict__ x,
    float* __restrict__ out)
{
    const int blk = blockIdx.x;
    const int c = blk & (CH-1);
    const int b = blk >> 6;
    const int d = threadIdx.x;
    __shared__ float sB[LC][16], sC[LC][16];
    __shared__ unsigned short gs[LC][264];

    if (d < 128) {
        const int l = d >> 2, q = (d & 3) * 4;
        *(float4*)&sB[l][q] = *(const float4*)&Bv[((size_t)b*LL + c*LC + l)*NN + q];
    } else {
        const int dd = d - 128;
        const int l = dd >> 2, q = (dd & 3) * 4;
        *(float4*)&sC[l][q] = *(const float4*)&Cv[((size_t)b*LL + c*LC + l)*NN + q];
    }
    float al[NN];
    bool fast = true;
    #pragma unroll
    for (int n = 0; n < NN; ++n) {
        al[n] = -expf(A_log[d*NN + n]) * 1.44269504f;
        fast = fast && (fabsf(al[n] - (n+1)*al[0]) <= 1e-3f*fabsf(al[n]) + 1e-6f);
    }
    float h[NN];
    const size_t ob = (size_t)blk * NN * DD + d;
    #pragma unroll
    for (int n = 0; n < NN; ++n) h[n] = Hin[ob + n*DD];
    const float dsk = Dskip[d];
    __syncthreads();
    if (fast) scan2_impl<true >(delta, xln, sB, sC, gs, al, b, c, d, h, dsk);
    else      scan2_impl<false>(delta, xln, sB, sC, gs, al, b, c, d, h, dsk);
    __syncthreads();

    // ---- GLU GEMM phase: (32x256) @ (256x512), A from LDS gs, B from Wt (L2)
    const int w = d >> 6, lane = d & 63;
    const int cl = lane & 15, rq = lane >> 4;
    f32x4 acc[8];   // nf 0..3 = lo cols w*64+nf*16, nf 4..7 = hi cols 256+w*64+(nf-4)*16
    const f32x4 zz = {0.f,0.f,0.f,0.f};
    #pragma unroll
    for (int nf = 0; nf < 8; ++nf) acc[nf] = zz;
    f32x4 acc2[8];  // second M half (rows 16..31)
    #pragma unroll
    for (int nf = 0; nf < 8; ++nf) acc2[nf] = zz;

    #pragma unroll
    for (int k0 = 0; k0 < 256; k0 += 32) {
        const bf16x8 a0 = *(const bf16x8*)&gs[cl][k0 + rq*8];
        const bf16x8 a1 = *(const bf16x8*)&gs[16 + cl][k0 + rq*8];
        #pragma unroll
        for (int nf = 0; nf < 8; ++nf) {
            const int nrow = (nf < 4) ? (w*64 + nf*16 + cl)
                                      : (256 + w*64 + (nf-4)*16 + cl);
            const bf16x8 bfr = *(const bf16x8*)&Wt[(size_t)nrow*DD + k0 + rq*8];
            acc [nf] = __builtin_amdgcn_mfma_f32_16x16x32_bf16(a0, bfr, acc [nf], 0, 0, 0);
            acc2[nf] = __builtin_amdgcn_mfma_f32_16x16x32_bf16(a1, bfr, acc2[nf], 0, 0, 0);
        }
    }
    // ---- epilogue: bias, gate, skip, store
    const int l0 = c * LC;
    #pragma unroll
    for (int nf = 0; nf < 4; ++nf) {
        const int j = w*64 + nf*16 + cl;
        const float bL = gb[j];
        const float bH = gb[j + 256];
        #pragma unroll
        for (int rr = 0; rr < 4; ++rr) {
            {   // rows 0..15
                const int m = rq*4 + rr;
                const size_t o = ((size_t)b*LL + l0 + m)*DD + j;
                const float lo = acc[nf][rr] + bL;
                const float hi = acc[nf+4][rr] + bH;
                const float sg = 1.f / (1.f + exp2f(-1.44269504f * hi));
                out[o] = lo * sg + x[o];
            }
            {   // rows 16..31
                const int m = 16 + rq*4 + rr;
                const size_t o = ((size_t)b*LL + l0 + m)*DD + j;
                const float lo = acc2[nf][rr] + bL;
                const float hi = acc2[nf+4][rr] + bH;
                const float sg = 1.f / (1.f + exp2f(-1.44269504f * hi));
                out[o] = lo * sg + x[o];
            }
        }
    }
}

extern "C" void kernel_launch(void* const* d_in, const int* in_sizes, int n_in,
                              void* d_out, int out_size, void* d_ws, size_t ws_size,
                              hipStream_t stream)
{
    const float* x    = (const float*)d_in[0];
    const float* ln_w = (const float*)d_in[1];
    const float* ln_b = (const float*)d_in[2];
    const float* xpw  = (const float*)d_in[3];
    const float* dtw  = (const float*)d_in[4];
    const float* dtb  = (const float*)d_in[5];
    const float* alog = (const float*)d_in[6];
    const float* dsk  = (const float*)d_in[7];
    const float* gw   = (const float*)d_in[8];
    const float* gb   = (const float*)d_in[9];
    float* out = (float*)d_out;

    char* ws = (char*)d_ws;
    size_t off = 0;
    auto alloc = [&](size_t bytes) {
        char* p = ws + off; off += (bytes + 255) & ~(size_t)255; return p;
    };
    unsigned short* xln   = (unsigned short*)alloc((size_t)BB*LL*DD*2);
    unsigned short* delta = (unsigned short*)alloc((size_t)BB*LL*DD*2);
    float*          Bvp   = (float*)         alloc((size_t)BB*LL*NN*4);
    float*          Cvp   = (float*)         alloc((size_t)BB*LL*NN*4);
    float*          S     = (float*)         alloc((size_t)BB*CH*NN*DD*4);
    float*          Dsum  = (float*)         alloc((size_t)BB*CH*DD*4);
    float*          Hin   = (float*)         alloc((size_t)BB*CH*NN*DD*4);
    unsigned short* Wt    = (unsigned short*)alloc((size_t)512*256*2);
    unsigned short* Wxt   = (unsigned short*)alloc((size_t)64*256*2);

    k_prep_wx<<<16, 256, 0, stream>>>(xpw, Wxt);
    k_transpose<<<dim3(16, 8), 256, 0, stream>>>(gw, Wt);
    k_ln_fused<<<1024, 256, 0, stream>>>(x, ln_w, ln_b, Wxt, dtw, dtb, xln, delta, Bvp, Cvp);
    k_scan1<<<BB*CH, 256, 0, stream>>>(delta, xln, Bvp, alog, S, Dsum);
    k_combine<<<256, 256, 0, stream>>>(S, Dsum, alog, Hin);
    k_scan2glu<<<BB*CH, 256, 0, stream>>>(delta, xln, Bvp, Cvp, alog, Hin, dsk, Wt, gb, x, out);
}

// Round 7
// 117.729 us; speedup vs baseline: 1.0890x; 1.0890x over previous
//
#include <hip/hip_runtime.h>
#include <hip/hip_bf16.h>

#define BB 16
#define LL 2048
#define DD 256
#define NN 16
#define RR 16
#define CH 64
#define LC (LL/CH)   /* 32 */

static __device__ __forceinline__ float bf2f(unsigned short u) {
    return __uint_as_float(((unsigned)u) << 16);
}
static __device__ __forceinline__ unsigned short f2bf(float f) {
    unsigned u = __float_as_uint(f);
    u += 0x7FFFu + ((u >> 16) & 1u);
    return (unsigned short)(u >> 16);
}

typedef __attribute__((ext_vector_type(8))) short bf16x8;
typedef __attribute__((ext_vector_type(4))) short bf16x4;
typedef __attribute__((ext_vector_type(4))) float f32x4;

// e[n] = E^(n+1), depth-4 product tree (full-rate VALU instead of trans pipe)
static __device__ __forceinline__ void pow_tree(float E, float* e) {
    e[0] = E;
    e[1] = E * E;
    e[2] = e[1] * E;
    e[3] = e[1] * e[1];
    e[4] = e[3] * e[0];  e[5] = e[3] * e[1];  e[6] = e[3] * e[2];  e[7] = e[3] * e[3];
    e[8] = e[7] * e[0];  e[9] = e[7] * e[1];  e[10] = e[7] * e[2]; e[11] = e[7] * e[3];
    e[12] = e[7] * e[4]; e[13] = e[7] * e[5]; e[14] = e[7] * e[6]; e[15] = e[7] * e[7];
}

// ---------------------------------------------------------------------------
// prep: Wxt[n][k] = xw[k][n] (bf16, n padded 48->64 with zeros). grid 16x256
// ---------------------------------------------------------------------------
__global__ __launch_bounds__(256) void k_prep_wx(
    const float* __restrict__ xw, unsigned short* __restrict__ Wxt)
{
    const int idx = blockIdx.x * 256 + threadIdx.x;   // 0..4095
    const int n  = idx >> 6;
    const int k0 = (idx & 63) * 4;
    #pragma unroll
    for (int i = 0; i < 4; ++i) {
        float v = (n < 48) ? xw[(size_t)(k0 + i) * 48 + n] : 0.f;
        Wxt[(size_t)n * DD + k0 + i] = f2bf(v);
    }
}

// ---------------------------------------------------------------------------
// Transpose glu_w (256x512 fp32) -> Wt (512x256 bf16)
// ---------------------------------------------------------------------------
__global__ __launch_bounds__(256) void k_transpose(
    const float* __restrict__ W, unsigned short* __restrict__ Wt)
{
    __shared__ unsigned short s[32][33];
    const int bx = blockIdx.x; // n tile (16)
    const int by = blockIdx.y; // k tile (8)
    const int t = threadIdx.x;
    const int r = t >> 5, cc = t & 31;
    #pragma unroll
    for (int i = 0; i < 4; ++i)
        s[r + 8*i][cc] = f2bf(W[(size_t)(by*32 + r + 8*i)*512 + bx*32 + cc]);
    __syncthreads();
    #pragma unroll
    for (int i = 0; i < 4; ++i)
        Wt[(size_t)(bx*32 + r + 8*i)*256 + by*32 + cc] = s[cc][r + 8*i];
}

// ---------------------------------------------------------------------------
// Kernel A (fused): LN + x_proj MFMA + dt_proj + softplus.
// 32 rows/block, 1024 blocks, 256 threads. Small operands in LDS.
// ---------------------------------------------------------------------------
__global__ __launch_bounds__(256) void k_ln_fused(
    const float* __restrict__ x,
    const float* __restrict__ ln_w,
    const float* __restrict__ ln_b,
    const unsigned short* __restrict__ Wxt,  // 64x256 bf16
    const float* __restrict__ dtw,           // 16x256
    const float* __restrict__ dtb,           // 256
    unsigned short* __restrict__ xln,
    unsigned short* __restrict__ delta,
    float* __restrict__ Bv,
    float* __restrict__ Cv)
{
    const int t = threadIdx.x;
    const int m0 = blockIdx.x * 32;
    const int row = t >> 3, seg = t & 7;
    const int grow = m0 + row;

    __shared__ unsigned short As[32][264];
    __shared__ float sdt[32][20];
    __shared__ float sdtw[16*256];
    __shared__ float slnw[256], slnb[256], sdtb[256];

    // ---- stage small operands into LDS
    {
        const int tt = t & 63;
        if (t < 64)       *(float4*)&slnw[tt*4] = *(const float4*)&ln_w[tt*4];
        else if (t < 128) *(float4*)&slnb[tt*4] = *(const float4*)&ln_b[tt*4];
        else if (t < 192) *(float4*)&sdtb[tt*4] = *(const float4*)&dtb[tt*4];
        #pragma unroll
        for (int k = 0; k < 4; ++k)
            *(float4*)&sdtw[(k*256 + t)*4] = *(const float4*)&dtw[(k*256 + t)*4];
    }

    // ---- load x (strided map) into registers
    float v[32];
    #pragma unroll
    for (int i = 0; i < 8; ++i)
        *(float4*)&v[i*4] = *(const float4*)(x + (size_t)grow*DD + i*32 + seg*4);

    // ---- LN stats: intra-thread + 8-lane shuffle reduce
    float s = 0.f, q = 0.f;
    #pragma unroll
    for (int i = 0; i < 32; ++i) { s += v[i]; q = fmaf(v[i], v[i], q); }
    #pragma unroll
    for (int o = 1; o < 8; o <<= 1) {
        s += __shfl_xor(s, o);
        q += __shfl_xor(q, o);
    }
    const float mu = s * (1.f/DD);
    const float rs = rsqrtf(q * (1.f/DD) - mu*mu + 1e-5f);
    __syncthreads();   // staging complete

    // ---- normalize, cast, write global + LDS A-tile
    unsigned short o16[32];
    #pragma unroll
    for (int i = 0; i < 8; ++i) {
        const int c = i*32 + seg*4;
        const float4 wv = *(const float4*)&slnw[c];
        const float4 bv = *(const float4*)&slnb[c];
        o16[i*4+0] = f2bf((v[i*4+0]-mu)*rs*wv.x + bv.x);
        o16[i*4+1] = f2bf((v[i*4+1]-mu)*rs*wv.y + bv.y);
        o16[i*4+2] = f2bf((v[i*4+2]-mu)*rs*wv.z + bv.z);
        o16[i*4+3] = f2bf((v[i*4+3]-mu)*rs*wv.w + bv.w);
    }
    #pragma unroll
    for (int i = 0; i < 8; ++i) {
        const int c = i*32 + seg*4;
        *(bf16x4*)&xln[(size_t)grow*DD + c] = *(bf16x4*)&o16[i*4];
        *(bf16x4*)&As[row][c]               = *(bf16x4*)&o16[i*4];
    }
    __syncthreads();

    // ---- x_proj MFMA: (32x256)@(256x48), B-fragments direct from global Wxt
    const int w = t >> 6, lane = t & 63;
    const int cl = lane & 15, rq = lane >> 4;
    const int mh = (w & 1) * 16;
    const int nh = (w >> 1) * 32;
    f32x4 acc0 = {0.f,0.f,0.f,0.f}, acc1 = {0.f,0.f,0.f,0.f};
    #pragma unroll
    for (int k0 = 0; k0 < 256; k0 += 32) {
        const bf16x8 a  = *(const bf16x8*)&As[mh + cl][k0 + rq*8];
        const bf16x8 b0 = *(const bf16x8*)&Wxt[(size_t)(nh + cl)*DD + k0 + rq*8];
        acc0 = __builtin_amdgcn_mfma_f32_16x16x32_bf16(a, b0, acc0, 0, 0, 0);
        if (w < 2) {
            const bf16x8 b1 = *(const bf16x8*)&Wxt[(size_t)(nh + 16 + cl)*DD + k0 + rq*8];
            acc1 = __builtin_amdgcn_mfma_f32_16x16x32_bf16(a, b1, acc1, 0, 0, 0);
        }
    }
    if (w < 2) {   // cols 0..15 -> dt (LDS), cols 16..31 -> Bv
        #pragma unroll
        for (int r = 0; r < 4; ++r) {
            sdt[mh + rq*4 + r][cl] = acc0[r];
            Bv[(size_t)(m0 + mh + rq*4 + r)*NN + cl] = acc1[r];
        }
    } else {       // cols 32..47 -> Cv
        #pragma unroll
        for (int r = 0; r < 4; ++r)
            Cv[(size_t)(m0 + mh + rq*4 + r)*NN + cl] = acc0[r];
    }
    __syncthreads();

    // ---- dt_proj (K=16) + softplus, all operands from LDS
    float dt[16];
    #pragma unroll
    for (int j = 0; j < 16; ++j) dt[j] = sdt[row][j];
    #pragma unroll
    for (int i = 0; i < 8; ++i) {
        const int c = i*32 + seg*4;
        float4 a4 = *(const float4*)&sdtb[c];
        #pragma unroll
        for (int j = 0; j < 16; ++j) {
            const float4 w4 = *(const float4*)&sdtw[j*256 + c];
            a4.x = fmaf(dt[j], w4.x, a4.x);
            a4.y = fmaf(dt[j], w4.y, a4.y);
            a4.z = fmaf(dt[j], w4.z, a4.z);
            a4.w = fmaf(dt[j], w4.w, a4.w);
        }
        unsigned short d16[4];
        #pragma unroll
        for (int jj = 0; jj < 4; ++jj) {
            const float ac = (&a4.x)[jj];
            const float sp = (ac > 15.f) ? ac
                : 0.69314718f * log2f(1.f + exp2f(ac * 1.44269504f));
            d16[jj] = f2bf(sp);
        }
        *(bf16x4*)&delta[(size_t)grow*DD + c] = *(bf16x4*)&d16[0];
    }
}

// ---------------------------------------------------------------------------
// scan pass 1 — chunk tiles (delta,xln) staged to LDS first, scan is pure
// LDS+VALU. grid B*CH, 256 thr.
// ---------------------------------------------------------------------------
template<bool FAST>
__device__ __forceinline__ void scan1_impl(
    const unsigned short (*sD)[264], const unsigned short (*sX)[264],
    const float (*sB)[16],
    const float* al, int d, float* h, float* dsum)
{
    #pragma unroll 4
    for (int l = 0; l < LC; ++l) {
        const float dl = bf2f(sD[l][d]);
        const float xl = bf2f(sX[l][d]);
        const float dx = dl * xl;
        *dsum += dl;
        float e[NN];
        if (FAST) pow_tree(exp2f(al[0]*dl), e);
        else {
            #pragma unroll
            for (int n = 0; n < NN; ++n) e[n] = exp2f(al[n]*dl);
        }
        #pragma unroll
        for (int n = 0; n < NN; ++n)
            h[n] = fmaf(e[n], h[n], dx * sB[l][n]);
    }
}

__global__ __launch_bounds__(256) void k_scan1(
    const unsigned short* __restrict__ delta,
    const unsigned short* __restrict__ xln,
    const float* __restrict__ Bv,
    const float* __restrict__ A_log,
    float* __restrict__ S, float* __restrict__ Dsum)
{
    const int blk = blockIdx.x;
    const int c = blk & (CH-1);
    const int b = blk >> 6;
    const int d = threadIdx.x;
    const int l0 = c * LC;
    __shared__ unsigned short sD[LC][264];
    __shared__ unsigned short sX[LC][264];
    __shared__ float sB[LC][16];

    // ---- stage chunk tiles
    {
        const int sr = d >> 3, sc = (d & 7) * 32;
        const size_t gbase = ((size_t)b*LL + l0 + sr)*DD + sc;
        #pragma unroll
        for (int i = 0; i < 4; ++i) {
            *(bf16x8*)&sD[sr][sc + i*8] = *(const bf16x8*)&delta[gbase + i*8];
            *(bf16x8*)&sX[sr][sc + i*8] = *(const bf16x8*)&xln  [gbase + i*8];
        }
        if (d < 128) {
            const int l = d >> 2, qq = (d & 3) * 4;
            *(float4*)&sB[l][qq] = *(const float4*)&Bv[((size_t)b*LL + l0 + l)*NN + qq];
        }
    }
    float al[NN];
    bool fast = true;
    #pragma unroll
    for (int n = 0; n < NN; ++n) {
        al[n] = -expf(A_log[d*NN + n]) * 1.44269504f;
        fast = fast && (fabsf(al[n] - (n+1)*al[0]) <= 1e-3f*fabsf(al[n]) + 1e-6f);
    }
    float h[NN];
    #pragma unroll
    for (int n = 0; n < NN; ++n) h[n] = 0.f;
    float dsum = 0.f;
    __syncthreads();
    if (fast) scan1_impl<true >(sD, sX, sB, al, d, h, &dsum);
    else      scan1_impl<false>(sD, sX, sB, al, d, h, &dsum);
    const size_t o = (size_t)blk * NN * DD + d;
    #pragma unroll
    for (int n = 0; n < NN; ++n) S[o + n*DD] = h[n];
    Dsum[(size_t)blk*DD + d] = dsum;
}

// ---------------------------------------------------------------------------
// combine: sequential fold over chunks -> per-chunk incoming state Hin.
// block = (b,n), threads = d. 8-deep load batching to hide latency.
// ---------------------------------------------------------------------------
__global__ __launch_bounds__(256) void k_combine(
    const float* __restrict__ S, const float* __restrict__ Dsum,
    const float* __restrict__ A_log, float* __restrict__ Hin)
{
    const int bi = blockIdx.x;
    const int d = threadIdx.x;
    const int n = bi & 15;
    const int b = bi >> 4;
    const float al = -expf(A_log[d*NN + n]) * 1.44269504f;
    float h = 0.f;
    for (int c0 = 0; c0 < CH; c0 += 8) {
        float ds8[8], s8[8];
        #pragma unroll
        for (int i = 0; i < 8; ++i) {
            const size_t blk = (size_t)b*CH + c0 + i;
            ds8[i] = Dsum[blk*DD + d];
            s8[i]  = S[(blk*NN + n)*DD + d];
        }
        #pragma unroll
        for (int i = 0; i < 8; ++i) {
            const size_t blk = (size_t)b*CH + c0 + i;
            Hin[(blk*NN + n)*DD + d] = h;
            h = fmaf(exp2f(al * ds8[i]), h, s8[i]);
        }
    }
}

// ---------------------------------------------------------------------------
// scan pass 2 — LDS-staged like scan1, produces g = gelu(y) (aliases delta)
// ---------------------------------------------------------------------------
template<bool FAST>
__device__ __forceinline__ void scan2_impl(
    const unsigned short (*sD)[264], const unsigned short (*sX)[264],
    const float (*sB)[16], const float (*sC)[16],
    const float* al, int d, float* h, float dsk,
    size_t gout, unsigned short* __restrict__ g)
{
    #pragma unroll 4
    for (int l = 0; l < LC; ++l) {
        const float dl = bf2f(sD[l][d]);
        const float xl = bf2f(sX[l][d]);
        const float dx = dl * xl;
        float e[NN];
        if (FAST) pow_tree(exp2f(al[0]*dl), e);
        else {
            #pragma unroll
            for (int n = 0; n < NN; ++n) e[n] = exp2f(al[n]*dl);
        }
        float y = 0.f;
        #pragma unroll
        for (int n = 0; n < NN; ++n) {
            h[n] = fmaf(e[n], h[n], dx * sB[l][n]);
            y = fmaf(h[n], sC[l][n], y);
        }
        const float vv = y + xl * dsk;
        // gelu (tanh form)
        const float u  = 0.7978845608f * (vv + 0.044715f*vv*vv*vv);
        const float t2 = exp2f(2.8853900818f * u);
        const float th = 1.f - 2.f/(t2 + 1.f);
        g[gout + (size_t)l*DD] = f2bf(0.5f * vv * (1.f + th));
    }
}

__global__ __launch_bounds__(256) void k_scan2(
    const unsigned short* __restrict__ delta,
    const unsigned short* __restrict__ xln,
    const float* __restrict__ Bv,
    const float* __restrict__ Cv,
    const float* __restrict__ A_log,
    const float* __restrict__ Hin,
    const float* __restrict__ Dskip,
    unsigned short* __restrict__ g)
{
    const int blk = blockIdx.x;
    const int c = blk & (CH-1);
    const int b = blk >> 6;
    const int d = threadIdx.x;
    const int l0 = c * LC;
    __shared__ unsigned short sD[LC][264];
    __shared__ unsigned short sX[LC][264];
    __shared__ float sB[LC][16], sC[LC][16];

    {
        const int sr = d >> 3, sc = (d & 7) * 32;
        const size_t gbase = ((size_t)b*LL + l0 + sr)*DD + sc;
        #pragma unroll
        for (int i = 0; i < 4; ++i) {
            *(bf16x8*)&sD[sr][sc + i*8] = *(const bf16x8*)&delta[gbase + i*8];
            *(bf16x8*)&sX[sr][sc + i*8] = *(const bf16x8*)&xln  [gbase + i*8];
        }
        if (d < 128) {
            const int l = d >> 2, qq = (d & 3) * 4;
            *(float4*)&sB[l][qq] = *(const float4*)&Bv[((size_t)b*LL + l0 + l)*NN + qq];
        } else {
            const int dd = d - 128;
            const int l = dd >> 2, qq = (dd & 3) * 4;
            *(float4*)&sC[l][qq] = *(const float4*)&Cv[((size_t)b*LL + l0 + l)*NN + qq];
        }
    }
    float al[NN];
    bool fast = true;
    #pragma unroll
    for (int n = 0; n < NN; ++n) {
        al[n] = -expf(A_log[d*NN + n]) * 1.44269504f;
        fast = fast && (fabsf(al[n] - (n+1)*al[0]) <= 1e-3f*fabsf(al[n]) + 1e-6f);
    }
    float h[NN];
    const size_t ob = (size_t)blk * NN * DD + d;
    #pragma unroll
    for (int n = 0; n < NN; ++n) h[n] = Hin[ob + n*DD];
    const float dsk = Dskip[d];
    __syncthreads();
    const size_t gout = ((size_t)b*LL + l0)*DD + d;
    if (fast) scan2_impl<true >(sD, sX, sB, sC, al, d, h, dsk, gout, g);
    else      scan2_impl<false>(sD, sX, sB, sC, al, d, h, dsk, gout, g);
}

// ---------------------------------------------------------------------------
// GLU GEMM (32768x256 @ 256x512) + bias + sigmoid gate + skip
// ---------------------------------------------------------------------------
__global__ __launch_bounds__(256) void k_glu(
    const unsigned short* __restrict__ g,
    const unsigned short* __restrict__ Wt,
    const float* __restrict__ gb,
    const float* __restrict__ x,
    float* __restrict__ out)
{
    __shared__ unsigned short As[64][40];
    __shared__ unsigned short Bl[64][40];
    __shared__ unsigned short Bh[64][40];
    const int n0 = blockIdx.x * 64;
    const int m0 = blockIdx.y * 64;
    const int t = threadIdx.x;
    const int w = t >> 6, lane = t & 63;
    const int r = t >> 2, q = t & 3;
    const int cl = lane & 15, rq = lane >> 4;
    f32x4 accL[4], accH[4];
    const f32x4 zz = {0.f, 0.f, 0.f, 0.f};
    #pragma unroll
    for (int nf = 0; nf < 4; ++nf) { accL[nf] = zz; accH[nf] = zz; }

    for (int k0 = 0; k0 < 256; k0 += 32) {
        *(bf16x8*)(&As[r][q*8]) = *(const bf16x8*)(&g [(size_t)(m0+r)*DD + k0 + q*8]);
        *(bf16x8*)(&Bl[r][q*8]) = *(const bf16x8*)(&Wt[(size_t)(n0+r)*DD + k0 + q*8]);
        *(bf16x8*)(&Bh[r][q*8]) = *(const bf16x8*)(&Wt[(size_t)(n0+256+r)*DD + k0 + q*8]);
        __syncthreads();
        const bf16x8 a = *(const bf16x8*)(&As[w*16 + cl][rq*8]);
        #pragma unroll
        for (int nf = 0; nf < 4; ++nf) {
            const bf16x8 bl = *(const bf16x8*)(&Bl[nf*16 + cl][rq*8]);
            const bf16x8 bh = *(const bf16x8*)(&Bh[nf*16 + cl][rq*8]);
            accL[nf] = __builtin_amdgcn_mfma_f32_16x16x32_bf16(a, bl, accL[nf], 0, 0, 0);
            accH[nf] = __builtin_amdgcn_mfma_f32_16x16x32_bf16(a, bh, accH[nf], 0, 0, 0);
        }
        __syncthreads();
    }
    #pragma unroll
    for (int nf = 0; nf < 4; ++nf) {
        const int j = n0 + nf*16 + cl;
        const float bL = gb[j];
        const float bH = gb[j + 256];
        #pragma unroll
        for (int rr = 0; rr < 4; ++rr) {
            const int m = m0 + w*16 + rq*4 + rr;
            const float lo = accL[nf][rr] + bL;
            const float hi = accH[nf][rr] + bH;
            const float sg = 1.f / (1.f + exp2f(-1.44269504f * hi));
            out[(size_t)m*DD + j] = lo * sg + x[(size_t)m*DD + j];
        }
    }
}

extern "C" void kernel_launch(void* const* d_in, const int* in_sizes, int n_in,
                              void* d_out, int out_size, void* d_ws, size_t ws_size,
                              hipStream_t stream)
{
    const float* x    = (const float*)d_in[0];
    const float* ln_w = (const float*)d_in[1];
    const float* ln_b = (const float*)d_in[2];
    const float* xpw  = (const float*)d_in[3];
    const float* dtw  = (const float*)d_in[4];
    const float* dtb  = (const float*)d_in[5];
    const float* alog = (const float*)d_in[6];
    const float* dsk  = (const float*)d_in[7];
    const float* gw   = (const float*)d_in[8];
    const float* gb   = (const float*)d_in[9];
    float* out = (float*)d_out;

    char* ws = (char*)d_ws;
    size_t off = 0;
    auto alloc = [&](size_t bytes) {
        char* p = ws + off; off += (bytes + 255) & ~(size_t)255; return p;
    };
    unsigned short* xln   = (unsigned short*)alloc((size_t)BB*LL*DD*2);
    unsigned short* delta = (unsigned short*)alloc((size_t)BB*LL*DD*2);
    float*          Bvp   = (float*)         alloc((size_t)BB*LL*NN*4);
    float*          Cvp   = (float*)         alloc((size_t)BB*LL*NN*4);
    float*          S     = (float*)         alloc((size_t)BB*CH*NN*DD*4);
    float*          Dsum  = (float*)         alloc((size_t)BB*CH*DD*4);
    float*          Hin   = (float*)         alloc((size_t)BB*CH*NN*DD*4);
    unsigned short* Wt    = (unsigned short*)alloc((size_t)512*256*2);
    unsigned short* Wxt   = (unsigned short*)alloc((size_t)64*256*2);
    unsigned short* g     = delta;   // alias: scan2 overwrites delta in place

    k_prep_wx<<<16, 256, 0, stream>>>(xpw, Wxt);
    k_transpose<<<dim3(16, 8), 256, 0, stream>>>(gw, Wt);
    k_ln_fused<<<1024, 256, 0, stream>>>(x, ln_w, ln_b, Wxt, dtw, dtb, xln, delta, Bvp, Cvp);
    k_scan1<<<BB*CH, 256, 0, stream>>>(delta, xln, Bvp, alog, S, Dsum);
    k_combine<<<256, 256, 0, stream>>>(S, Dsum, alog, Hin);
    k_scan2<<<BB*CH, 256, 0, stream>>>(delta, xln, Bvp, Cvp, alog, Hin, dsk, g);
    k_glu<<<dim3(4, 512), 256, 0, stream>>>(g, Wt, gb, x, out);
}

// Round 8
// 116.619 us; speedup vs baseline: 1.0993x; 1.0095x over previous
//
#include <hip/hip_runtime.h>
#include <hip/hip_bf16.h>

#define BB 16
#define LL 2048
#define DD 256
#define NN 16
#define RR 16
#define CH 64
#define LC (LL/CH)   /* 32 */

static __device__ __forceinline__ float bf2f(unsigned short u) {
    return __uint_as_float(((unsigned)u) << 16);
}
static __device__ __forceinline__ unsigned short f2bf(float f) {
    unsigned u = __float_as_uint(f);
    u += 0x7FFFu + ((u >> 16) & 1u);
    return (unsigned short)(u >> 16);
}

typedef __attribute__((ext_vector_type(8))) short bf16x8;
typedef __attribute__((ext_vector_type(4))) short bf16x4;
typedef __attribute__((ext_vector_type(4))) float f32x4;

// e[n] = E^(n+1), depth-4 product tree (full-rate VALU instead of trans pipe)
static __device__ __forceinline__ void pow_tree(float E, float* e) {
    e[0] = E;
    e[1] = E * E;
    e[2] = e[1] * E;
    e[3] = e[1] * e[1];
    e[4] = e[3] * e[0];  e[5] = e[3] * e[1];  e[6] = e[3] * e[2];  e[7] = e[3] * e[3];
    e[8] = e[7] * e[0];  e[9] = e[7] * e[1];  e[10] = e[7] * e[2]; e[11] = e[7] * e[3];
    e[12] = e[7] * e[4]; e[13] = e[7] * e[5]; e[14] = e[7] * e[6]; e[15] = e[7] * e[7];
}

// ---------------------------------------------------------------------------
// prep: Wxt[n][k] = xw[k][n] (bf16, n padded 48->64 with zeros). grid 16x256
// ---------------------------------------------------------------------------
__global__ __launch_bounds__(256) void k_prep_wx(
    const float* __restrict__ xw, unsigned short* __restrict__ Wxt)
{
    const int idx = blockIdx.x * 256 + threadIdx.x;   // 0..4095
    const int n  = idx >> 6;
    const int k0 = (idx & 63) * 4;
    #pragma unroll
    for (int i = 0; i < 4; ++i) {
        float v = (n < 48) ? xw[(size_t)(k0 + i) * 48 + n] : 0.f;
        Wxt[(size_t)n * DD + k0 + i] = f2bf(v);
    }
}

// ---------------------------------------------------------------------------
// Transpose glu_w (256x512 fp32) -> Wt (512x256 bf16)
// ---------------------------------------------------------------------------
__global__ __launch_bounds__(256) void k_transpose(
    const float* __restrict__ W, unsigned short* __restrict__ Wt)
{
    __shared__ unsigned short s[32][33];
    const int bx = blockIdx.x; // n tile (16)
    const int by = blockIdx.y; // k tile (8)
    const int t = threadIdx.x;
    const int r = t >> 5, cc = t & 31;
    #pragma unroll
    for (int i = 0; i < 4; ++i)
        s[r + 8*i][cc] = f2bf(W[(size_t)(by*32 + r + 8*i)*512 + bx*32 + cc]);
    __syncthreads();
    #pragma unroll
    for (int i = 0; i < 4; ++i)
        Wt[(size_t)(bx*32 + r + 8*i)*256 + by*32 + cc] = s[cc][r + 8*i];
}

// ---------------------------------------------------------------------------
// Fused: LN + x_proj MFMA + COLUMN-wise dt_proj + softplus + scan pass 1.
// Block = chunk (b,c) = 32 consecutive rows. Thread d owns column d in the
// dt/scan phase (delta values never leave registers before the scan).
// ---------------------------------------------------------------------------
template<bool FAST>
__device__ __forceinline__ void dt_scan1(
    const float (*sdt)[20], const unsigned short (*As)[264],
    const float (*sB)[16], const float* wj, float bia,
    const float* al, int d, size_t m0,
    unsigned short* __restrict__ delta,
    float* h, float* dsum)
{
    #pragma unroll 4
    for (int l = 0; l < LC; ++l) {
        float acc = bia;
        #pragma unroll
        for (int j = 0; j < 16; ++j)
            acc = fmaf(sdt[l][j], wj[j], acc);
        const float sp = (acc > 15.f) ? acc
            : 0.69314718f * log2f(1.f + exp2f(acc * 1.44269504f));
        const unsigned short dbits = f2bf(sp);
        delta[(m0 + l)*DD + d] = dbits;
        const float dl = bf2f(dbits);       // rounded: matches scan2 exactly
        const float xl = bf2f(As[l][d]);
        const float dx = dl * xl;
        *dsum += dl;
        float e[NN];
        if (FAST) pow_tree(exp2f(al[0]*dl), e);
        else {
            #pragma unroll
            for (int n = 0; n < NN; ++n) e[n] = exp2f(al[n]*dl);
        }
        #pragma unroll
        for (int n = 0; n < NN; ++n)
            h[n] = fmaf(e[n], h[n], dx * sB[l][n]);
    }
}

__global__ __launch_bounds__(256) void k_ln_scan1(
    const float* __restrict__ x,
    const float* __restrict__ ln_w,
    const float* __restrict__ ln_b,
    const unsigned short* __restrict__ Wxt,  // 64x256 bf16
    const float* __restrict__ dtw,           // 16x256
    const float* __restrict__ dtb,           // 256
    const float* __restrict__ A_log,
    unsigned short* __restrict__ xln,
    unsigned short* __restrict__ delta,
    float* __restrict__ Bv,
    float* __restrict__ Cv,
    float* __restrict__ S,
    float* __restrict__ Dsum)
{
    const int t = threadIdx.x;
    const int blk = blockIdx.x;          // = b*CH + c
    const size_t m0 = (size_t)blk * 32;  // global row base
    const int row = t >> 3, seg = t & 7;
    const size_t grow = m0 + row;

    __shared__ unsigned short As[32][264];
    __shared__ float sdt[32][20];
    __shared__ float sB[32][16];
    __shared__ float slnw[256], slnb[256], sdtb[256];

    // ---- stage small vectors
    {
        const int tt = t & 63;
        if (t < 64)       *(float4*)&slnw[tt*4] = *(const float4*)&ln_w[tt*4];
        else if (t < 128) *(float4*)&slnb[tt*4] = *(const float4*)&ln_b[tt*4];
        else if (t < 192) *(float4*)&sdtb[tt*4] = *(const float4*)&dtb[tt*4];
    }

    // ---- per-thread dtw column + A row (L2-resident, coalesced)
    float wj[16];
    #pragma unroll
    for (int j = 0; j < 16; ++j) wj[j] = dtw[j*DD + t];
    float al[NN];
    bool fast = true;
    #pragma unroll
    for (int n = 0; n < NN; ++n) {
        al[n] = -expf(A_log[t*NN + n]) * 1.44269504f;
        fast = fast && (fabsf(al[n] - (n+1)*al[0]) <= 1e-3f*fabsf(al[n]) + 1e-6f);
    }

    // ---- load x (strided map) + LN stats
    float v[32];
    #pragma unroll
    for (int i = 0; i < 8; ++i)
        *(float4*)&v[i*4] = *(const float4*)(x + grow*DD + i*32 + seg*4);
    float s = 0.f, q = 0.f;
    #pragma unroll
    for (int i = 0; i < 32; ++i) { s += v[i]; q = fmaf(v[i], v[i], q); }
    #pragma unroll
    for (int o = 1; o < 8; o <<= 1) {
        s += __shfl_xor(s, o);
        q += __shfl_xor(q, o);
    }
    const float mu = s * (1.f/DD);
    const float rs = rsqrtf(q * (1.f/DD) - mu*mu + 1e-5f);
    __syncthreads();   // staging complete

    // ---- normalize, cast, write global + LDS A-tile
    #pragma unroll
    for (int i = 0; i < 8; ++i) {
        const int c = i*32 + seg*4;
        const float4 wv = *(const float4*)&slnw[c];
        const float4 bv = *(const float4*)&slnb[c];
        unsigned short o16[4];
        o16[0] = f2bf((v[i*4+0]-mu)*rs*wv.x + bv.x);
        o16[1] = f2bf((v[i*4+1]-mu)*rs*wv.y + bv.y);
        o16[2] = f2bf((v[i*4+2]-mu)*rs*wv.z + bv.z);
        o16[3] = f2bf((v[i*4+3]-mu)*rs*wv.w + bv.w);
        *(bf16x4*)&xln[grow*DD + c] = *(bf16x4*)&o16[0];
        *(bf16x4*)&As[row][c]       = *(bf16x4*)&o16[0];
    }
    __syncthreads();

    // ---- x_proj MFMA: (32x256)@(256x48), B-fragments direct from global Wxt
    {
        const int w = t >> 6, lane = t & 63;
        const int cl = lane & 15, rq = lane >> 4;
        const int mh = (w & 1) * 16;
        const int nh = (w >> 1) * 32;
        f32x4 acc0 = {0.f,0.f,0.f,0.f}, acc1 = {0.f,0.f,0.f,0.f};
        #pragma unroll
        for (int k0 = 0; k0 < 256; k0 += 32) {
            const bf16x8 a  = *(const bf16x8*)&As[mh + cl][k0 + rq*8];
            const bf16x8 b0 = *(const bf16x8*)&Wxt[(size_t)(nh + cl)*DD + k0 + rq*8];
            acc0 = __builtin_amdgcn_mfma_f32_16x16x32_bf16(a, b0, acc0, 0, 0, 0);
            if (w < 2) {
                const bf16x8 b1 = *(const bf16x8*)&Wxt[(size_t)(nh + 16 + cl)*DD + k0 + rq*8];
                acc1 = __builtin_amdgcn_mfma_f32_16x16x32_bf16(a, b1, acc1, 0, 0, 0);
            }
        }
        if (w < 2) {   // cols 0..15 -> dt (LDS); cols 16..31 -> Bv global + sB LDS
            #pragma unroll
            for (int r = 0; r < 4; ++r) {
                const int rr = mh + rq*4 + r;
                sdt[rr][cl] = acc0[r];
                sB[rr][cl]  = acc1[r];
                Bv[(m0 + rr)*NN + cl] = acc1[r];
            }
        } else {       // cols 32..47 -> Cv
            #pragma unroll
            for (int r = 0; r < 4; ++r)
                Cv[(m0 + mh + rq*4 + r)*NN + cl] = acc0[r];
        }
    }
    __syncthreads();

    // ---- column dt_proj + softplus + scan pass 1 (thread t = column d)
    float h[NN];
    #pragma unroll
    for (int n = 0; n < NN; ++n) h[n] = 0.f;
    float dsum = 0.f;
    const float bia = sdtb[t];
    if (fast) dt_scan1<true >(sdt, As, sB, wj, bia, al, t, m0, delta, h, &dsum);
    else      dt_scan1<false>(sdt, As, sB, wj, bia, al, t, m0, delta, h, &dsum);
    const size_t o = (size_t)blk * NN * DD + t;
    #pragma unroll
    for (int n = 0; n < NN; ++n) S[o + n*DD] = h[n];
    Dsum[(size_t)blk*DD + t] = dsum;
}

// ---------------------------------------------------------------------------
// combine: sequential fold over chunks -> per-chunk incoming state Hin.
// block = (b,n), threads = d. 8-deep load batching to hide latency.
// ---------------------------------------------------------------------------
__global__ __launch_bounds__(256) void k_combine(
    const float* __restrict__ S, const float* __restrict__ Dsum,
    const float* __restrict__ A_log, float* __restrict__ Hin)
{
    const int bi = blockIdx.x;
    const int d = threadIdx.x;
    const int n = bi & 15;
    const int b = bi >> 4;
    const float al = -expf(A_log[d*NN + n]) * 1.44269504f;
    float h = 0.f;
    for (int c0 = 0; c0 < CH; c0 += 8) {
        float ds8[8], s8[8];
        #pragma unroll
        for (int i = 0; i < 8; ++i) {
            const size_t blk = (size_t)b*CH + c0 + i;
            ds8[i] = Dsum[blk*DD + d];
            s8[i]  = S[(blk*NN + n)*DD + d];
        }
        #pragma unroll
        for (int i = 0; i < 8; ++i) {
            const size_t blk = (size_t)b*CH + c0 + i;
            Hin[(blk*NN + n)*DD + d] = h;
            h = fmaf(exp2f(al * ds8[i]), h, s8[i]);
        }
    }
}

// ---------------------------------------------------------------------------
// scan pass 2 — LDS-staged, produces g = gelu(y) (aliases delta)
// ---------------------------------------------------------------------------
template<bool FAST>
__device__ __forceinline__ void scan2_impl(
    const unsigned short (*sD)[264], const unsigned short (*sX)[264],
    const float (*sB)[16], const float (*sC)[16],
    const float* al, int d, float* h, float dsk,
    size_t gout, unsigned short* __restrict__ g)
{
    #pragma unroll 4
    for (int l = 0; l < LC; ++l) {
        const float dl = bf2f(sD[l][d]);
        const float xl = bf2f(sX[l][d]);
        const float dx = dl * xl;
        float e[NN];
        if (FAST) pow_tree(exp2f(al[0]*dl), e);
        else {
            #pragma unroll
            for (int n = 0; n < NN; ++n) e[n] = exp2f(al[n]*dl);
        }
        float yb[4] = {0.f, 0.f, 0.f, 0.f};   // 4-bank y accumulation
        #pragma unroll
        for (int n = 0; n < NN; ++n) {
            h[n] = fmaf(e[n], h[n], dx * sB[l][n]);
            yb[n & 3] = fmaf(h[n], sC[l][n], yb[n & 3]);
        }
        const float vv = (yb[0]+yb[1]) + (yb[2]+yb[3]) + xl * dsk;
        // gelu (tanh form)
        const float u  = 0.7978845608f * (vv + 0.044715f*vv*vv*vv);
        const float t2 = exp2f(2.8853900818f * u);
        const float th = 1.f - 2.f/(t2 + 1.f);
        g[gout + (size_t)l*DD] = f2bf(0.5f * vv * (1.f + th));
    }
}

__global__ __launch_bounds__(256) void k_scan2(
    const unsigned short* __restrict__ delta,
    const unsigned short* __restrict__ xln,
    const float* __restrict__ Bv,
    const float* __restrict__ Cv,
    const float* __restrict__ A_log,
    const float* __restrict__ Hin,
    const float* __restrict__ Dskip,
    unsigned short* __restrict__ g)
{
    const int blk = blockIdx.x;
    const int c = blk & (CH-1);
    const int b = blk >> 6;
    const int d = threadIdx.x;
    const int l0 = c * LC;
    __shared__ unsigned short sD[LC][264];
    __shared__ unsigned short sX[LC][264];
    __shared__ float sB[LC][16], sC[LC][16];

    {
        const int sr = d >> 3, sc = (d & 7) * 32;
        const size_t gbase = ((size_t)b*LL + l0 + sr)*DD + sc;
        #pragma unroll
        for (int i = 0; i < 4; ++i) {
            *(bf16x8*)&sD[sr][sc + i*8] = *(const bf16x8*)&delta[gbase + i*8];
            *(bf16x8*)&sX[sr][sc + i*8] = *(const bf16x8*)&xln  [gbase + i*8];
        }
        if (d < 128) {
            const int l = d >> 2, qq = (d & 3) * 4;
            *(float4*)&sB[l][qq] = *(const float4*)&Bv[((size_t)b*LL + l0 + l)*NN + qq];
        } else {
            const int dd = d - 128;
            const int l = dd >> 2, qq = (dd & 3) * 4;
            *(float4*)&sC[l][qq] = *(const float4*)&Cv[((size_t)b*LL + l0 + l)*NN + qq];
        }
    }
    float al[NN];
    bool fast = true;
    #pragma unroll
    for (int n = 0; n < NN; ++n) {
        al[n] = -expf(A_log[d*NN + n]) * 1.44269504f;
        fast = fast && (fabsf(al[n] - (n+1)*al[0]) <= 1e-3f*fabsf(al[n]) + 1e-6f);
    }
    float h[NN];
    const size_t ob = (size_t)blk * NN * DD + d;
    #pragma unroll
    for (int n = 0; n < NN; ++n) h[n] = Hin[ob + n*DD];
    const float dsk = Dskip[d];
    __syncthreads();
    const size_t gout = ((size_t)b*LL + l0)*DD + d;
    if (fast) scan2_impl<true >(sD, sX, sB, sC, al, d, h, dsk, gout, g);
    else      scan2_impl<false>(sD, sX, sB, sC, al, d, h, dsk, gout, g);
}

// ---------------------------------------------------------------------------
// GLU GEMM (32768x256 @ 256x512) + bias + sigmoid gate + skip
// ---------------------------------------------------------------------------
__global__ __launch_bounds__(256) void k_glu(
    const unsigned short* __restrict__ g,
    const unsigned short* __restrict__ Wt,
    const float* __restrict__ gb,
    const float* __restrict__ x,
    float* __restrict__ out)
{
    __shared__ unsigned short As[64][40];
    __shared__ unsigned short Bl[64][40];
    __shared__ unsigned short Bh[64][40];
    const int n0 = blockIdx.x * 64;
    const int m0 = blockIdx.y * 64;
    const int t = threadIdx.x;
    const int w = t >> 6, lane = t & 63;
    const int r = t >> 2, q = t & 3;
    const int cl = lane & 15, rq = lane >> 4;
    f32x4 accL[4], accH[4];
    const f32x4 zz = {0.f, 0.f, 0.f, 0.f};
    #pragma unroll
    for (int nf = 0; nf < 4; ++nf) { accL[nf] = zz; accH[nf] = zz; }

    for (int k0 = 0; k0 < 256; k0 += 32) {
        *(bf16x8*)(&As[r][q*8]) = *(const bf16x8*)(&g [(size_t)(m0+r)*DD + k0 + q*8]);
        *(bf16x8*)(&Bl[r][q*8]) = *(const bf16x8*)(&Wt[(size_t)(n0+r)*DD + k0 + q*8]);
        *(bf16x8*)(&Bh[r][q*8]) = *(const bf16x8*)(&Wt[(size_t)(n0+256+r)*DD + k0 + q*8]);
        __syncthreads();
        const bf16x8 a = *(const bf16x8*)(&As[w*16 + cl][rq*8]);
        #pragma unroll
        for (int nf = 0; nf < 4; ++nf) {
            const bf16x8 bl = *(const bf16x8*)(&Bl[nf*16 + cl][rq*8]);
            const bf16x8 bh = *(const bf16x8*)(&Bh[nf*16 + cl][rq*8]);
            accL[nf] = __builtin_amdgcn_mfma_f32_16x16x32_bf16(a, bl, accL[nf], 0, 0, 0);
            accH[nf] = __builtin_amdgcn_mfma_f32_16x16x32_bf16(a, bh, accH[nf], 0, 0, 0);
        }
        __syncthreads();
    }
    #pragma unroll
    for (int nf = 0; nf < 4; ++nf) {
        const int j = n0 + nf*16 + cl;
        const float bL = gb[j];
        const float bH = gb[j + 256];
        #pragma unroll
        for (int rr = 0; rr < 4; ++rr) {
            const int m = m0 + w*16 + rq*4 + rr;
            const float lo = accL[nf][rr] + bL;
            const float hi = accH[nf][rr] + bH;
            const float sg = 1.f / (1.f + exp2f(-1.44269504f * hi));
            out[(size_t)m*DD + j] = lo * sg + x[(size_t)m*DD + j];
        }
    }
}

extern "C" void kernel_launch(void* const* d_in, const int* in_sizes, int n_in,
                              void* d_out, int out_size, void* d_ws, size_t ws_size,
                              hipStream_t stream)
{
    const float* x    = (const float*)d_in[0];
    const float* ln_w = (const float*)d_in[1];
    const float* ln_b = (const float*)d_in[2];
    const float* xpw  = (const float*)d_in[3];
    const float* dtw  = (const float*)d_in[4];
    const float* dtb  = (const float*)d_in[5];
    const float* alog = (const float*)d_in[6];
    const float* dsk  = (const float*)d_in[7];
    const float* gw   = (const float*)d_in[8];
    const float* gb   = (const float*)d_in[9];
    float* out = (float*)d_out;

    char* ws = (char*)d_ws;
    size_t off = 0;
    auto alloc = [&](size_t bytes) {
        char* p = ws + off; off += (bytes + 255) & ~(size_t)255; return p;
    };
    unsigned short* xln   = (unsigned short*)alloc((size_t)BB*LL*DD*2);
    unsigned short* delta = (unsigned short*)alloc((size_t)BB*LL*DD*2);
    float*          Bvp   = (float*)         alloc((size_t)BB*LL*NN*4);
    float*          Cvp   = (float*)         alloc((size_t)BB*LL*NN*4);
    float*          S     = (float*)         alloc((size_t)BB*CH*NN*DD*4);
    float*          Dsum  = (float*)         alloc((size_t)BB*CH*DD*4);
    float*          Hin   = (float*)         alloc((size_t)BB*CH*NN*DD*4);
    unsigned short* Wt    = (unsigned short*)alloc((size_t)512*256*2);
    unsigned short* Wxt   = (unsigned short*)alloc((size_t)64*256*2);
    unsigned short* g     = delta;   // alias: scan2 overwrites delta in place

    k_prep_wx<<<16, 256, 0, stream>>>(xpw, Wxt);
    k_transpose<<<dim3(16, 8), 256, 0, stream>>>(gw, Wt);
    k_ln_scan1<<<BB*CH, 256, 0, stream>>>(x, ln_w, ln_b, Wxt, dtw, dtb, alog,
                                          xln, delta, Bvp, Cvp, S, Dsum);
    k_combine<<<256, 256, 0, stream>>>(S, Dsum, alog, Hin);
    k_scan2<<<BB*CH, 256, 0, stream>>>(delta, xln, Bvp, Cvp, alog, Hin, dsk, g);
    k_glu<<<dim3(4, 512), 256, 0, stream>>>(g, Wt, gb, x, out);
}

// Round 10
// 110.123 us; speedup vs baseline: 1.1642x; 1.0590x over previous
//
#include <hip/hip_runtime.h>
#include <hip/hip_bf16.h>

#define BB 16
#define LL 2048
#define DD 256
#define NN 16
#define RR 16
// fused path: 32 chunks of 64 rows. fallback path: 64 chunks of 32 rows.
#define CHF 32
#define LCF 64
#define CHB 64
#define LCB 32

static __device__ __forceinline__ float bf2f(unsigned short u) {
    return __uint_as_float(((unsigned)u) << 16);
}
static __device__ __forceinline__ unsigned short f2bf(float f) {
    unsigned u = __float_as_uint(f);
    u += 0x7FFFu + ((u >> 16) & 1u);
    return (unsigned short)(u >> 16);
}

typedef __attribute__((ext_vector_type(8))) short bf16x8;
typedef __attribute__((ext_vector_type(4))) short bf16x4;
typedef __attribute__((ext_vector_type(4))) float f32x4;

// e[n] = E^(n+1), depth-4 product tree
static __device__ __forceinline__ void pow_tree(float E, float* e) {
    e[0] = E;
    e[1] = E * E;
    e[2] = e[1] * E;
    e[3] = e[1] * e[1];
    e[4] = e[3] * e[0];  e[5] = e[3] * e[1];  e[6] = e[3] * e[2];  e[7] = e[3] * e[3];
    e[8] = e[7] * e[0];  e[9] = e[7] * e[1];  e[10] = e[7] * e[2]; e[11] = e[7] * e[3];
    e[12] = e[7] * e[4]; e[13] = e[7] * e[5]; e[14] = e[7] * e[6]; e[15] = e[7] * e[7];
}

// Device-scope grid barrier (generation counting). Requires all blocks
// resident (gated host-side by occupancy query). cnt=bar[0], gen=bar[32].
static __device__ __forceinline__ void gridBarrier(unsigned* bar, unsigned nblk) {
    __threadfence();            // release: my stores visible device-scope
    __syncthreads();
    if (threadIdx.x == 0) {
        unsigned* cnt = bar;
        unsigned* gen = bar + 32;
        const unsigned gsnap = atomicAdd(gen, 0u);
        const unsigned arrived = atomicAdd(cnt, 1u) + 1u;
        if (arrived == nblk) {
            atomicExch(cnt, 0u);            // reset before release
            __threadfence();
            atomicAdd(gen, 1u);             // release waiters
        } else {
            while (atomicAdd(gen, 0u) == gsnap)
                __builtin_amdgcn_s_sleep(2);
        }
    }
    __syncthreads();
    __threadfence();            // acquire: see others' stores
}

// ---------------------------------------------------------------------------
// prep (merged): blocks 0..15 build Wxt (xw^T bf16, 48->64 pad);
// blocks 16..143 transpose glu_w -> Wt (512x256 bf16)
// ---------------------------------------------------------------------------
__global__ __launch_bounds__(256) void k_prep(
    const float* __restrict__ xw, const float* __restrict__ gw,
    unsigned short* __restrict__ Wxt, unsigned short* __restrict__ Wt)
{
    __shared__ unsigned short s[32][33];
    const int bid = blockIdx.x;
    const int t = threadIdx.x;
    if (bid < 16) {
        const int idx = bid * 256 + t;
        const int n  = idx >> 6;
        const int k0 = (idx & 63) * 4;
        #pragma unroll
        for (int i = 0; i < 4; ++i) {
            float v = (n < 48) ? xw[(size_t)(k0 + i) * 48 + n] : 0.f;
            Wxt[(size_t)n * DD + k0 + i] = f2bf(v);
        }
    } else {
        const int bb = bid - 16;
        const int bx = bb & 15, by = bb >> 4;
        const int r = t >> 5, cc = t & 31;
        #pragma unroll
        for (int i = 0; i < 4; ++i)
            s[r + 8*i][cc] = f2bf(gw[(size_t)(by*32 + r + 8*i)*512 + bx*32 + cc]);
        __syncthreads();
        #pragma unroll
        for (int i = 0; i < 4; ++i)
            Wt[(size_t)(bx*32 + r + 8*i)*256 + by*32 + cc] = s[cc][r + 8*i];
    }
}

// ===========================================================================
// PRIMARY: single fused kernel, 512 blocks (chunk = 64 rows), hand barrier.
// LN -> x_proj MFMA -> dt+scan1 -> BAR -> combine(blk<256) -> BAR -> scan2+gelu
// delta recomputed in phase 3 from persistent sdt LDS (bit-identical).
// ===========================================================================
template<bool FAST>
__device__ __forceinline__ void fused_scan1(
    const float (*sdt)[20], const unsigned short (*As)[264],
    const float (*sB)[17], const float* wj, float bia,
    const float* al, int t, float* h, float* dsum)
{
    #pragma unroll 4
    for (int l = 0; l < LCF; ++l) {
        float acc = bia;
        #pragma unroll
        for (int j = 0; j < 16; ++j)
            acc = fmaf(sdt[l][j], wj[j], acc);
        const float sp = (acc > 15.f) ? acc
            : 0.69314718f * log2f(1.f + exp2f(acc * 1.44269504f));
        const float dl = bf2f(f2bf(sp));
        const float xl = bf2f(As[l][t]);
        const float dx = dl * xl;
        *dsum += dl;
        float e[NN];
        if (FAST) pow_tree(exp2f(al[0]*dl), e);
        else {
            #pragma unroll
            for (int n = 0; n < NN; ++n) e[n] = exp2f(al[n]*dl);
        }
        #pragma unroll
        for (int n = 0; n < NN; ++n)
            h[n] = fmaf(e[n], h[n], dx * sB[l][n]);
    }
}

template<bool FAST>
__device__ __forceinline__ void fused_scan2(
    const float (*sdt)[20], const unsigned short (*As)[264],
    const float (*sB)[17], const float (*sC)[17],
    const float* wj, float bia, const float* al, int t,
    float* h, float dsk, size_t m0, unsigned short* __restrict__ g)
{
    #pragma unroll 4
    for (int l = 0; l < LCF; ++l) {
        float acc = bia;
        #pragma unroll
        for (int j = 0; j < 16; ++j)
            acc = fmaf(sdt[l][j], wj[j], acc);
        const float sp = (acc > 15.f) ? acc
            : 0.69314718f * log2f(1.f + exp2f(acc * 1.44269504f));
        const float dl = bf2f(f2bf(sp));
        const float xl = bf2f(As[l][t]);
        const float dx = dl * xl;
        float e[NN];
        if (FAST) pow_tree(exp2f(al[0]*dl), e);
        else {
            #pragma unroll
            for (int n = 0; n < NN; ++n) e[n] = exp2f(al[n]*dl);
        }
        float yb[4] = {0.f, 0.f, 0.f, 0.f};
        #pragma unroll
        for (int n = 0; n < NN; ++n) {
            h[n] = fmaf(e[n], h[n], dx * sB[l][n]);
            yb[n & 3] = fmaf(h[n], sC[l][n], yb[n & 3]);
        }
        const float vv = (yb[0]+yb[1]) + (yb[2]+yb[3]) + xl * dsk;
        const float u  = 0.7978845608f * (vv + 0.044715f*vv*vv*vv);
        const float t2 = exp2f(2.8853900818f * u);
        const float th = 1.f - 2.f/(t2 + 1.f);
        g[(m0 + l)*DD + t] = f2bf(0.5f * vv * (1.f + th));
    }
}

__global__ __launch_bounds__(256) void k_fused(
    const float* __restrict__ x,
    const float* __restrict__ ln_w,
    const float* __restrict__ ln_b,
    const unsigned short* __restrict__ Wxt,
    const float* __restrict__ dtw,
    const float* __restrict__ dtb,
    const float* __restrict__ A_log,
    const float* __restrict__ Dskip,
    float* __restrict__ S,
    float* __restrict__ Dsum,
    float* __restrict__ Hin,
    unsigned short* __restrict__ g,
    unsigned* __restrict__ bar)
{
    const int t = threadIdx.x;
    const int blk = blockIdx.x;            // b*CHF + c
    const size_t m0 = (size_t)blk * LCF;   // 64-row chunk base

    __shared__ unsigned short As[LCF][264];          // 33 KB, persists
    __shared__ float sdt[LCF][20];                   // persists (phase 3 reuse)
    __shared__ float sB[LCF][17];
    __shared__ float sC[LCF][17];
    __shared__ float slnw[256], slnb[256], sdtb[256];

    // ---- stage small vectors
    {
        const int tt = t & 63;
        if (t < 64)       *(float4*)&slnw[tt*4] = *(const float4*)&ln_w[tt*4];
        else if (t < 128) *(float4*)&slnb[tt*4] = *(const float4*)&ln_b[tt*4];
        else if (t < 192) *(float4*)&sdtb[tt*4] = *(const float4*)&dtb[tt*4];
    }

    // ---- per-thread (column t) constants
    float wj[16];
    #pragma unroll
    for (int j = 0; j < 16; ++j) wj[j] = dtw[j*DD + t];
    float al[NN];
    bool fast = true;
    #pragma unroll
    for (int n = 0; n < NN; ++n) {
        al[n] = -expf(A_log[t*NN + n]) * 1.44269504f;
        fast = fast && (fabsf(al[n] - (n+1)*al[0]) <= 1e-3f*fabsf(al[n]) + 1e-6f);
    }
    const float dsk = Dskip[t];
    __syncthreads();   // small-vector staging complete

    // ---- LN: two 32-row halves (8 threads/row, strided columns)
    const int seg = t & 7;
    #pragma unroll
    for (int half = 0; half < 2; ++half) {
        const int row = (t >> 3) + 32*half;
        const size_t grow = m0 + row;
        float v[32];
        #pragma unroll
        for (int i = 0; i < 8; ++i)
            *(float4*)&v[i*4] = *(const float4*)(x + grow*DD + i*32 + seg*4);
        float s = 0.f, q = 0.f;
        #pragma unroll
        for (int i = 0; i < 32; ++i) { s += v[i]; q = fmaf(v[i], v[i], q); }
        #pragma unroll
        for (int o = 1; o < 8; o <<= 1) {
            s += __shfl_xor(s, o);
            q += __shfl_xor(q, o);
        }
        const float mu = s * (1.f/DD);
        const float rs = rsqrtf(q * (1.f/DD) - mu*mu + 1e-5f);
        #pragma unroll
        for (int i = 0; i < 8; ++i) {
            const int c = i*32 + seg*4;
            const float4 wv = *(const float4*)&slnw[c];
            const float4 bv = *(const float4*)&slnb[c];
            unsigned short o16[4];
            o16[0] = f2bf((v[i*4+0]-mu)*rs*wv.x + bv.x);
            o16[1] = f2bf((v[i*4+1]-mu)*rs*wv.y + bv.y);
            o16[2] = f2bf((v[i*4+2]-mu)*rs*wv.z + bv.z);
            o16[3] = f2bf((v[i*4+3]-mu)*rs*wv.w + bv.w);
            *(bf16x4*)&As[row][c] = *(bf16x4*)&o16[0];
        }
    }
    __syncthreads();

    // ---- x_proj MFMA: (64x256)@(256x48). Wave w owns rows w*16..w*16+16,
    // computes 3 col-fragments (dt | B | C). B-frags direct from global Wxt.
    {
        const int w = t >> 6, lane = t & 63;
        const int cl = lane & 15, rq = lane >> 4;
        const int mrow = w * 16;
        f32x4 aDt = {0.f,0.f,0.f,0.f}, aB = {0.f,0.f,0.f,0.f}, aC = {0.f,0.f,0.f,0.f};
        #pragma unroll
        for (int k0 = 0; k0 < 256; k0 += 32) {
            const bf16x8 a  = *(const bf16x8*)&As[mrow + cl][k0 + rq*8];
            const bf16x8 b0 = *(const bf16x8*)&Wxt[(size_t)(cl)*DD      + k0 + rq*8];
            const bf16x8 b1 = *(const bf16x8*)&Wxt[(size_t)(16+cl)*DD   + k0 + rq*8];
            const bf16x8 b2 = *(const bf16x8*)&Wxt[(size_t)(32+cl)*DD   + k0 + rq*8];
            aDt = __builtin_amdgcn_mfma_f32_16x16x32_bf16(a, b0, aDt, 0, 0, 0);
            aB  = __builtin_amdgcn_mfma_f32_16x16x32_bf16(a, b1, aB,  0, 0, 0);
            aC  = __builtin_amdgcn_mfma_f32_16x16x32_bf16(a, b2, aC,  0, 0, 0);
        }
        #pragma unroll
        for (int r = 0; r < 4; ++r) {
            const int rr = mrow + rq*4 + r;
            sdt[rr][cl] = aDt[r];
            sB[rr][cl]  = aB[r];
            sC[rr][cl]  = aC[r];
        }
    }
    __syncthreads();

    // ---- phase 1: dt_proj + softplus + scan1 (thread t = column d)
    float h[NN];
    #pragma unroll
    for (int n = 0; n < NN; ++n) h[n] = 0.f;
    float dsum = 0.f;
    const float bia = sdtb[t];
    if (fast) fused_scan1<true >(sdt, As, sB, wj, bia, al, t, h, &dsum);
    else      fused_scan1<false>(sdt, As, sB, wj, bia, al, t, h, &dsum);
    {
        const size_t o = (size_t)blk * NN * DD + t;
        #pragma unroll
        for (int n = 0; n < NN; ++n) S[o + n*DD] = h[n];
        Dsum[(size_t)blk*DD + t] = dsum;
    }
    gridBarrier(bar, BB*CHF);

    // ---- phase 2: combine (blocks 0..255 = one (b,n) pair)
    if (blk < 256) {
        const int n2 = blk & 15, b2 = blk >> 4;
        const float al2 = -expf(A_log[t*NN + n2]) * 1.44269504f;
        float hh = 0.f;
        for (int c0 = 0; c0 < CHF; c0 += 16) {
            float ds16[16], s16[16];
            #pragma unroll
            for (int i = 0; i < 16; ++i) {
                const size_t bc = (size_t)b2*CHF + c0 + i;
                ds16[i] = Dsum[bc*DD + t];
                s16[i]  = S[(bc*NN + n2)*DD + t];
            }
            #pragma unroll
            for (int i = 0; i < 16; ++i) {
                const size_t bc = (size_t)b2*CHF + c0 + i;
                Hin[(bc*NN + n2)*DD + t] = hh;
                hh = fmaf(exp2f(al2 * ds16[i]), hh, s16[i]);
            }
        }
    }
    gridBarrier(bar, BB*CHF);

    // ---- phase 3: scan2 + gelu -> g (delta recomputed from sdt, bit-identical)
    {
        const size_t ob = (size_t)blk * NN * DD + t;
        #pragma unroll
        for (int n = 0; n < NN; ++n) h[n] = Hin[ob + n*DD];
    }
    if (fast) fused_scan2<true >(sdt, As, sB, sC, wj, bia, al, t, h, dsk, m0, g);
    else      fused_scan2<false>(sdt, As, sB, sC, wj, bia, al, t, h, dsk, m0, g);
}

// ===========================================================================
// FALLBACK (R8 verbatim, proven): k_ln_scan1 + k_combine + k_scan2
// ===========================================================================
template<bool FAST>
__device__ __forceinline__ void dt_scan1_fb(
    const float (*sdt)[20], const unsigned short (*As)[264],
    const float (*sB)[16], const float* wj, float bia,
    const float* al, int d, size_t m0,
    unsigned short* __restrict__ delta,
    float* h, float* dsum)
{
    #pragma unroll 4
    for (int l = 0; l < LCB; ++l) {
        float acc = bia;
        #pragma unroll
        for (int j = 0; j < 16; ++j)
            acc = fmaf(sdt[l][j], wj[j], acc);
        const float sp = (acc > 15.f) ? acc
            : 0.69314718f * log2f(1.f + exp2f(acc * 1.44269504f));
        const unsigned short dbits = f2bf(sp);
        delta[(m0 + l)*DD + d] = dbits;
        const float dl = bf2f(dbits);
        const float xl = bf2f(As[l][d]);
        const float dx = dl * xl;
        *dsum += dl;
        float e[NN];
        if (FAST) pow_tree(exp2f(al[0]*dl), e);
        else {
            #pragma unroll
            for (int n = 0; n < NN; ++n) e[n] = exp2f(al[n]*dl);
        }
        #pragma unroll
        for (int n = 0; n < NN; ++n)
            h[n] = fmaf(e[n], h[n], dx * sB[l][n]);
    }
}

__global__ __launch_bounds__(256) void k_ln_scan1(
    const float* __restrict__ x,
    const float* __restrict__ ln_w,
    const float* __restrict__ ln_b,
    const unsigned short* __restrict__ Wxt,
    const float* __restrict__ dtw,
    const float* __restrict__ dtb,
    const float* __restrict__ A_log,
    unsigned short* __restrict__ xln,
    unsigned short* __restrict__ delta,
    float* __restrict__ Bv,
    float* __restrict__ Cv,
    float* __restrict__ S,
    float* __restrict__ Dsum)
{
    const int t = threadIdx.x;
    const int blk = blockIdx.x;
    const size_t m0 = (size_t)blk * 32;
    const int row = t >> 3, seg = t & 7;
    const size_t grow = m0 + row;

    __shared__ unsigned short As[32][264];
    __shared__ float sdt[32][20];
    __shared__ float sB[32][16];
    __shared__ float slnw[256], slnb[256], sdtb[256];

    {
        const int tt = t & 63;
        if (t < 64)       *(float4*)&slnw[tt*4] = *(const float4*)&ln_w[tt*4];
        else if (t < 128) *(float4*)&slnb[tt*4] = *(const float4*)&ln_b[tt*4];
        else if (t < 192) *(float4*)&sdtb[tt*4] = *(const float4*)&dtb[tt*4];
    }
    float wj[16];
    #pragma unroll
    for (int j = 0; j < 16; ++j) wj[j] = dtw[j*DD + t];
    float al[NN];
    bool fast = true;
    #pragma unroll
    for (int n = 0; n < NN; ++n) {
        al[n] = -expf(A_log[t*NN + n]) * 1.44269504f;
        fast = fast && (fabsf(al[n] - (n+1)*al[0]) <= 1e-3f*fabsf(al[n]) + 1e-6f);
    }
    float v[32];
    #pragma unroll
    for (int i = 0; i < 8; ++i)
        *(float4*)&v[i*4] = *(const float4*)(x + grow*DD + i*32 + seg*4);
    float s = 0.f, q = 0.f;
    #pragma unroll
    for (int i = 0; i < 32; ++i) { s += v[i]; q = fmaf(v[i], v[i], q); }
    #pragma unroll
    for (int o = 1; o < 8; o <<= 1) {
        s += __shfl_xor(s, o);
        q += __shfl_xor(q, o);
    }
    const float mu = s * (1.f/DD);
    const float rs = rsqrtf(q * (1.f/DD) - mu*mu + 1e-5f);
    __syncthreads();
    #pragma unroll
    for (int i = 0; i < 8; ++i) {
        const int c = i*32 + seg*4;
        const float4 wv = *(const float4*)&slnw[c];
        const float4 bv = *(const float4*)&slnb[c];
        unsigned short o16[4];
        o16[0] = f2bf((v[i*4+0]-mu)*rs*wv.x + bv.x);
        o16[1] = f2bf((v[i*4+1]-mu)*rs*wv.y + bv.y);
        o16[2] = f2bf((v[i*4+2]-mu)*rs*wv.z + bv.z);
        o16[3] = f2bf((v[i*4+3]-mu)*rs*wv.w + bv.w);
        *(bf16x4*)&xln[grow*DD + c] = *(bf16x4*)&o16[0];
        *(bf16x4*)&As[row][c]       = *(bf16x4*)&o16[0];
    }
    __syncthreads();
    {
        const int w = t >> 6, lane = t & 63;
        const int cl = lane & 15, rq = lane >> 4;
        const int mh = (w & 1) * 16;
        const int nh = (w >> 1) * 32;
        f32x4 acc0 = {0.f,0.f,0.f,0.f}, acc1 = {0.f,0.f,0.f,0.f};
        #pragma unroll
        for (int k0 = 0; k0 < 256; k0 += 32) {
            const bf16x8 a  = *(const bf16x8*)&As[mh + cl][k0 + rq*8];
            const bf16x8 b0 = *(const bf16x8*)&Wxt[(size_t)(nh + cl)*DD + k0 + rq*8];
            acc0 = __builtin_amdgcn_mfma_f32_16x16x32_bf16(a, b0, acc0, 0, 0, 0);
            if (w < 2) {
                const bf16x8 b1 = *(const bf16x8*)&Wxt[(size_t)(nh + 16 + cl)*DD + k0 + rq*8];
                acc1 = __builtin_amdgcn_mfma_f32_16x16x32_bf16(a, b1, acc1, 0, 0, 0);
            }
        }
        if (w < 2) {
            #pragma unroll
            for (int r = 0; r < 4; ++r) {
                const int rr = mh + rq*4 + r;
                sdt[rr][cl] = acc0[r];
                sB[rr][cl]  = acc1[r];
                Bv[(m0 + rr)*NN + cl] = acc1[r];
            }
        } else {
            #pragma unroll
            for (int r = 0; r < 4; ++r)
                Cv[(m0 + mh + rq*4 + r)*NN + cl] = acc0[r];
        }
    }
    __syncthreads();
    float h[NN];
    #pragma unroll
    for (int n = 0; n < NN; ++n) h[n] = 0.f;
    float dsum = 0.f;
    const float bia = sdtb[t];
    if (fast) dt_scan1_fb<true >(sdt, As, sB, wj, bia, al, t, m0, delta, h, &dsum);
    else      dt_scan1_fb<false>(sdt, As, sB, wj, bia, al, t, m0, delta, h, &dsum);
    const size_t o = (size_t)blk * NN * DD + t;
    #pragma unroll
    for (int n = 0; n < NN; ++n) S[o + n*DD] = h[n];
    Dsum[(size_t)blk*DD + t] = dsum;
}

__global__ __launch_bounds__(256) void k_combine(
    const float* __restrict__ S, const float* __restrict__ Dsum,
    const float* __restrict__ A_log, float* __restrict__ Hin)
{
    const int bi = blockIdx.x;
    const int d = threadIdx.x;
    const int n = bi & 15;
    const int b = bi >> 4;
    const float al = -expf(A_log[d*NN + n]) * 1.44269504f;
    float h = 0.f;
    for (int c0 = 0; c0 < CHB; c0 += 8) {
        float ds8[8], s8[8];
        #pragma unroll
        for (int i = 0; i < 8; ++i) {
            const size_t blk = (size_t)b*CHB + c0 + i;
            ds8[i] = Dsum[blk*DD + d];
            s8[i]  = S[(blk*NN + n)*DD + d];
        }
        #pragma unroll
        for (int i = 0; i < 8; ++i) {
            const size_t blk = (size_t)b*CHB + c0 + i;
            Hin[(blk*NN + n)*DD + d] = h;
            h = fmaf(exp2f(al * ds8[i]), h, s8[i]);
        }
    }
}

template<bool FAST>
__device__ __forceinline__ void scan2_impl_fb(
    const unsigned short (*sD)[264], const unsigned short (*sX)[264],
    const float (*sB)[16], const float (*sC)[16],
    const float* al, int d, float* h, float dsk,
    size_t gout, unsigned short* __restrict__ g)
{
    #pragma unroll 4
    for (int l = 0; l < LCB; ++l) {
        const float dl = bf2f(sD[l][d]);
        const float xl = bf2f(sX[l][d]);
        const float dx = dl * xl;
        float e[NN];
        if (FAST) pow_tree(exp2f(al[0]*dl), e);
        else {
            #pragma unroll
            for (int n = 0; n < NN; ++n) e[n] = exp2f(al[n]*dl);
        }
        float yb[4] = {0.f, 0.f, 0.f, 0.f};
        #pragma unroll
        for (int n = 0; n < NN; ++n) {
            h[n] = fmaf(e[n], h[n], dx * sB[l][n]);
            yb[n & 3] = fmaf(h[n], sC[l][n], yb[n & 3]);
        }
        const float vv = (yb[0]+yb[1]) + (yb[2]+yb[3]) + xl * dsk;
        const float u  = 0.7978845608f * (vv + 0.044715f*vv*vv*vv);
        const float t2 = exp2f(2.8853900818f * u);
        const float th = 1.f - 2.f/(t2 + 1.f);
        g[gout + (size_t)l*DD] = f2bf(0.5f * vv * (1.f + th));
    }
}

__global__ __launch_bounds__(256) void k_scan2(
    const unsigned short* __restrict__ delta,
    const unsigned short* __restrict__ xln,
    const float* __restrict__ Bv,
    const float* __restrict__ Cv,
    const float* __restrict__ A_log,
    const float* __restrict__ Hin,
    const float* __restrict__ Dskip,
    unsigned short* __restrict__ g)
{
    const int blk = blockIdx.x;
    const int c = blk & (CHB-1);
    const int b = blk >> 6;
    const int d = threadIdx.x;
    const int l0 = c * LCB;
    __shared__ unsigned short sD[LCB][264];
    __shared__ unsigned short sX[LCB][264];
    __shared__ float sB[LCB][16], sC[LCB][16];
    {
        const int sr = d >> 3, sc = (d & 7) * 32;
        const size_t gbase = ((size_t)b*LL + l0 + sr)*DD + sc;
        #pragma unroll
        for (int i = 0; i < 4; ++i) {
            *(bf16x8*)&sD[sr][sc + i*8] = *(const bf16x8*)&delta[gbase + i*8];
            *(bf16x8*)&sX[sr][sc + i*8] = *(const bf16x8*)&xln  [gbase + i*8];
        }
        if (d < 128) {
            const int l = d >> 2, qq = (d & 3) * 4;
            *(float4*)&sB[l][qq] = *(const float4*)&Bv[((size_t)b*LL + l0 + l)*NN + qq];
        } else {
            const int dd = d - 128;
            const int l = dd >> 2, qq = (dd & 3) * 4;
            *(float4*)&sC[l][qq] = *(const float4*)&Cv[((size_t)b*LL + l0 + l)*NN + qq];
        }
    }
    float al[NN];
    bool fast = true;
    #pragma unroll
    for (int n = 0; n < NN; ++n) {
        al[n] = -expf(A_log[d*NN + n]) * 1.44269504f;
        fast = fast && (fabsf(al[n] - (n+1)*al[0]) <= 1e-3f*fabsf(al[n]) + 1e-6f);
    }
    float h[NN];
    const size_t ob = (size_t)blk * NN * DD + d;
    #pragma unroll
    for (int n = 0; n < NN; ++n) h[n] = Hin[ob + n*DD];
    const float dsk = Dskip[d];
    __syncthreads();
    const size_t gout = ((size_t)b*LL + l0)*DD + d;
    if (fast) scan2_impl_fb<true >(sD, sX, sB, sC, al, d, h, dsk, gout, g);
    else      scan2_impl_fb<false>(sD, sX, sB, sC, al, d, h, dsk, gout, g);
}

// ---------------------------------------------------------------------------
// GLU GEMM (32768x256 @ 256x512) + bias + sigmoid gate + skip
// ---------------------------------------------------------------------------
__global__ __launch_bounds__(256) void k_glu(
    const unsigned short* __restrict__ g,
    const unsigned short* __restrict__ Wt,
    const float* __restrict__ gb,
    const float* __restrict__ x,
    float* __restrict__ out)
{
    __shared__ unsigned short As[64][40];
    __shared__ unsigned short Bl[64][40];
    __shared__ unsigned short Bh[64][40];
    const int n0 = blockIdx.x * 64;
    const int m0 = blockIdx.y * 64;
    const int t = threadIdx.x;
    const int w = t >> 6, lane = t & 63;
    const int r = t >> 2, q = t & 3;
    const int cl = lane & 15, rq = lane >> 4;
    f32x4 accL[4], accH[4];
    const f32x4 zz = {0.f, 0.f, 0.f, 0.f};
    #pragma unroll
    for (int nf = 0; nf < 4; ++nf) { accL[nf] = zz; accH[nf] = zz; }

    for (int k0 = 0; k0 < 256; k0 += 32) {
        *(bf16x8*)(&As[r][q*8]) = *(const bf16x8*)(&g [(size_t)(m0+r)*DD + k0 + q*8]);
        *(bf16x8*)(&Bl[r][q*8]) = *(const bf16x8*)(&Wt[(size_t)(n0+r)*DD + k0 + q*8]);
        *(bf16x8*)(&Bh[r][q*8]) = *(const bf16x8*)(&Wt[(size_t)(n0+256+r)*DD + k0 + q*8]);
        __syncthreads();
        const bf16x8 a = *(const bf16x8*)(&As[w*16 + cl][rq*8]);
        #pragma unroll
        for (int nf = 0; nf < 4; ++nf) {
            const bf16x8 bl = *(const bf16x8*)(&Bl[nf*16 + cl][rq*8]);
            const bf16x8 bh = *(const bf16x8*)(&Bh[nf*16 + cl][rq*8]);
            accL[nf] = __builtin_amdgcn_mfma_f32_16x16x32_bf16(a, bl, accL[nf], 0, 0, 0);
            accH[nf] = __builtin_amdgcn_mfma_f32_16x16x32_bf16(a, bh, accH[nf], 0, 0, 0);
        }
        __syncthreads();
    }
    #pragma unroll
    for (int nf = 0; nf < 4; ++nf) {
        const int j = n0 + nf*16 + cl;
        const float bL = gb[j];
        const float bH = gb[j + 256];
        #pragma unroll
        for (int rr = 0; rr < 4; ++rr) {
            const int m = m0 + w*16 + rq*4 + rr;
            const float lo = accL[nf][rr] + bL;
            const float hi = accH[nf][rr] + bH;
            const float sg = 1.f / (1.f + exp2f(-1.44269504f * hi));
            out[(size_t)m*DD + j] = lo * sg + x[(size_t)m*DD + j];
        }
    }
}

extern "C" void kernel_launch(void* const* d_in, const int* in_sizes, int n_in,
                              void* d_out, int out_size, void* d_ws, size_t ws_size,
                              hipStream_t stream)
{
    const float* x    = (const float*)d_in[0];
    const float* ln_w = (const float*)d_in[1];
    const float* ln_b = (const float*)d_in[2];
    const float* xpw  = (const float*)d_in[3];
    const float* dtw  = (const float*)d_in[4];
    const float* dtb  = (const float*)d_in[5];
    const float* alog = (const float*)d_in[6];
    const float* dsk  = (const float*)d_in[7];
    const float* gw   = (const float*)d_in[8];
    const float* gb   = (const float*)d_in[9];
    float* out = (float*)d_out;

    char* ws = (char*)d_ws;
    size_t off = 0;
    auto alloc = [&](size_t bytes) {
        char* p = ws + off; off += (bytes + 255) & ~(size_t)255; return p;
    };
    unsigned*       bar    = (unsigned*)      alloc(256);
    unsigned short* xln    = (unsigned short*)alloc((size_t)BB*LL*DD*2);
    unsigned short* deltaG = (unsigned short*)alloc((size_t)BB*LL*DD*2);
    float*          Bvp    = (float*)         alloc((size_t)BB*LL*NN*4);
    float*          Cvp    = (float*)         alloc((size_t)BB*LL*NN*4);
    float*          S      = (float*)         alloc((size_t)BB*CHB*NN*DD*4);
    float*          Dsum   = (float*)         alloc((size_t)BB*CHB*DD*4);
    float*          Hin    = (float*)         alloc((size_t)BB*CHB*NN*DD*4);
    unsigned short* Wt     = (unsigned short*)alloc((size_t)512*256*2);
    unsigned short* Wxt    = (unsigned short*)alloc((size_t)64*256*2);
    unsigned short* g      = deltaG;   // g shares the delta buffer in both paths

    k_prep<<<144, 256, 0, stream>>>(xpw, gw, Wxt, Wt);

    // capture-safe host queries: can all 512 fused blocks be co-resident?
    int occ = 0, ncu = 0, dev = 0;
    bool coop = false;
    if (hipGetDevice(&dev) == hipSuccess &&
        hipOccupancyMaxActiveBlocksPerMultiprocessor(&occ, k_fused, 256, 0) == hipSuccess &&
        hipDeviceGetAttribute(&ncu, hipDeviceAttributeMultiprocessorCount, dev) == hipSuccess)
        coop = (occ * ncu >= BB*CHF);

    if (coop) {
        hipMemsetAsync(bar, 0, 256, stream);
        k_fused<<<BB*CHF, 256, 0, stream>>>(x, ln_w, ln_b, Wxt, dtw, dtb, alog,
                                            dsk, S, Dsum, Hin, g, bar);
    } else {
        k_ln_scan1<<<BB*CHB, 256, 0, stream>>>(x, ln_w, ln_b, Wxt, dtw, dtb, alog,
                                               xln, deltaG, Bvp, Cvp, S, Dsum);
        k_combine<<<256, 256, 0, stream>>>(S, Dsum, alog, Hin);
        k_scan2<<<BB*CHB, 256, 0, stream>>>(deltaG, xln, Bvp, Cvp, alog, Hin, dsk, g);
    }

    k_glu<<<dim3(4, 512), 256, 0, stream>>>(g, Wt, gb, x, out);
}